// Round 10
// baseline (309.131 us; speedup 1.0000x reference)
//
#include <hip/hip_runtime.h>
#include <hip/hip_bf16.h>
#include <math.h>

#define B_    32
#define C_    1280
#define H_    32
#define W_    32
#define N_    6890
#define HID_  256
#define MID_  128
#define HW_   (H_ * W_)
#define KSTEP 32
#define KITER (C_ / KSTEP)   // 40
#define LSTR  20             // LDS row stride in uints (16B-aligned frag starts)

typedef __attribute__((ext_vector_type(8))) short short8v;
typedef __attribute__((ext_vector_type(4))) float f32x4;

static __device__ __forceinline__ uint pkbf(float a, float b) {
    union { __hip_bfloat16 h; ushort u; } ua, ub;
    ua.h = __float2bfloat16(a);
    ub.h = __float2bfloat16(b);
    return (uint)ua.u | ((uint)ub.u << 16);
}

// ---------------------------------------------------------------------------
// Kernel 1: Wcomb = reduce_w @ cls_w1 in bf16 MFMA-B-fragment linear order:
//   Bpack[((ks*8 + nb)*64 + lane)*8 + i] = Wcomb[k][n]
//   k = ks*32 + 8*(lane>>4) + i,  n = nb*16 + (lane&15)
// Last block computes bcomb[m] = cls_b1[m] + reduce_b @ cls_w1.
// 4 independent partial accumulators break the dependent-FMA chain
// (256 serial fma @4cy = 1024cy -> ~300cy).
// ---------------------------------------------------------------------------
__global__ __launch_bounds__(256) void k_wcomb(
        const float* __restrict__ rw, const float* __restrict__ w1,
        const float* __restrict__ b1, const float* __restrict__ rb,
        __hip_bfloat16* __restrict__ bpack, float* __restrict__ bcomb) {
    if (blockIdx.x == (C_ * MID_) / 256) {
        int m = threadIdx.x;
        if (m < MID_) {
            float a0 = b1[m], a1 = 0.f, a2 = 0.f, a3 = 0.f;
#pragma unroll 4
            for (int d = 0; d < HID_; d += 4) {
                a0 = fmaf(rb[d + 0], w1[(d + 0) * MID_ + m], a0);
                a1 = fmaf(rb[d + 1], w1[(d + 1) * MID_ + m], a1);
                a2 = fmaf(rb[d + 2], w1[(d + 2) * MID_ + m], a2);
                a3 = fmaf(rb[d + 3], w1[(d + 3) * MID_ + m], a3);
            }
            bcomb[m] = (a0 + a1) + (a2 + a3);
        }
        return;
    }
    int o = blockIdx.x * 256 + threadIdx.x;
    int c = o >> 7, m = o & 127;
    const float* rwc = rw + (size_t)c * HID_;
    float a0 = 0.f, a1 = 0.f, a2 = 0.f, a3 = 0.f;
#pragma unroll 4
    for (int d = 0; d < HID_; d += 4) {
        a0 = fmaf(rwc[d + 0], w1[(d + 0) * MID_ + m], a0);
        a1 = fmaf(rwc[d + 1], w1[(d + 1) * MID_ + m], a1);
        a2 = fmaf(rwc[d + 2], w1[(d + 2) * MID_ + m], a2);
        a3 = fmaf(rwc[d + 3], w1[(d + 3) * MID_ + m], a3);
    }
    float acc = (a0 + a1) + (a2 + a3);

    int ks = c >> 5, kr = c & 31;
    int lh = kr >> 3, ii = kr & 7;
    int nb = m >> 4, col = m & 15;
    size_t idx = ((size_t)((ks * 8 + nb) * 64 + lh * 16 + col)) * 8 + ii;
    bpack[idx] = __float2bfloat16(acc);
}

// ---------------------------------------------------------------------------
// Kernel 2: fred[b][p][n] (bf16) = sum_c feat[b][c][p] * Wcomb[c][n] via MFMA.
// Block: batch b, 64 px x 128 n; 4 waves, wave w owns n in [32w,32w+32).
// A staged bf16 pair-packed in LDS (double-buffered, XOR bank swizzle),
// 1 barrier/step. A is register-prefetched TWO K-steps ahead (manual
// unroll-by-2, static slots) to cover ~900cy HBM latency at 2 waves/SIMD;
// B (L2-resident) stays 1-deep.
// Hazard note: reads of buf X at step s precede barrier s+1; rewrites of
// buf X occur after barrier s+1 -> one barrier/step remains race-free.
// ---------------------------------------------------------------------------
__global__ __launch_bounds__(256) void k_pregemm(
        const float* __restrict__ feat,
        const __hip_bfloat16* __restrict__ bpack,
        __hip_bfloat16* __restrict__ fredh) {
    const int b  = blockIdx.y;
    const int p0 = blockIdx.x * 64;
    const float* F = feat + (size_t)b * C_ * HW_ + p0;

    __shared__ uint As[2][64][LSTR];   // bf16 pairs: uint col c holds k=2c,2c+1

    const int t  = threadIdx.x;
    const int wv = t >> 6;
    const int l  = t & 63;

    // staging geometry: lanes 0..7 cover 128B contiguous pixels of one k-row
    const int pl   = l & 7;                       // pixel group
    const int ql   = l >> 3;                      // k-pair sub-index
    const int pair = (wv & 1) * 8 + ql;           // k-pair 0..15 (k=2*pair,+1)
    const int px0  = 4 * pl + 32 * (wv >> 1);     // pixel base
    // bank-spread swizzle on the pair column (write side): inject px bits 3,4
    const int wcol = pair ^ ((((px0 >> 3) & 1) << 3) | (((px0 >> 4) & 1) << 2));

    // MFMA fragment geometry
    const int arow = l & 15;                      // A row (pixel) in 16-block
    const int g    = l >> 4;                      // k-octet 0..3
    const int crd  = (4 * g) ^ (((arow >> 3) & 1) << 3);  // read col base (pre-mi)

    f32x4 acc[4][2];
#pragma unroll
    for (int mi = 0; mi < 4; ++mi)
#pragma unroll
        for (int nb = 0; nb < 2; ++nb) acc[mi][nb] = (f32x4)0.f;

    const short8v* Bp = (const short8v*)bpack;

    const size_t ro0 = (size_t)(2 * pair + 0) * HW_ + px0;
    const size_t ro1 = (size_t)(2 * pair + 1) * HW_ + px0;

    // prologue: 2-deep A prefetch (steps 0 and 1), 1-deep B (step 0)
    float4 r0a = *(const float4*)&F[ro0];
    float4 r1a = *(const float4*)&F[ro1];
    const float* F1 = F + (size_t)KSTEP * HW_;
    float4 r0b = *(const float4*)&F1[ro0];
    float4 r1b = *(const float4*)&F1[ro1];
    short8v b0c = Bp[(size_t)(wv * 2 + 0) * 64 + l];
    short8v b1c = Bp[(size_t)(wv * 2 + 1) * 64 + l];

    for (int i = 0; i < KITER / 2; ++i) {
        const int s0 = 2 * i, s1 = 2 * i + 1;

        // ---- step s0: buffer 0, register slot A ----
        {
            const float* q0 = (const float*)&r0a;
            const float* q1 = (const float*)&r1a;
#pragma unroll
            for (int j = 0; j < 4; ++j)
                As[0][px0 + j][wcol] = pkbf(q0[j], q1[j]);
        }
        __syncthreads();
        if (s0 + 2 < KITER) {                       // prefetch step s0+2
            const float* Fn = F + (size_t)(s0 + 2) * KSTEP * HW_;
            r0a = *(const float4*)&Fn[ro0];
            r1a = *(const float4*)&Fn[ro1];
        }
        short8v b0n = Bp[(size_t)(s1 * 8 + wv * 2 + 0) * 64 + l];
        short8v b1n = Bp[(size_t)(s1 * 8 + wv * 2 + 1) * 64 + l];
#pragma unroll
        for (int mi = 0; mi < 4; ++mi) {
            short8v afr = *(const short8v*)&As[0][16 * mi + arow][crd ^ ((mi & 1) << 2)];
            acc[mi][0] = __builtin_amdgcn_mfma_f32_16x16x32_bf16(afr, b0c, acc[mi][0], 0, 0, 0);
            acc[mi][1] = __builtin_amdgcn_mfma_f32_16x16x32_bf16(afr, b1c, acc[mi][1], 0, 0, 0);
        }
        b0c = b0n; b1c = b1n;

        // ---- step s1: buffer 1, register slot B ----
        {
            const float* q0 = (const float*)&r0b;
            const float* q1 = (const float*)&r1b;
#pragma unroll
            for (int j = 0; j < 4; ++j)
                As[1][px0 + j][wcol] = pkbf(q0[j], q1[j]);
        }
        __syncthreads();
        if (s1 + 2 < KITER) {                       // prefetch step s1+2
            const float* Fn = F + (size_t)(s1 + 2) * KSTEP * HW_;
            r0b = *(const float4*)&Fn[ro0];
            r1b = *(const float4*)&Fn[ro1];
        }
        if (s1 + 1 < KITER) {
            b0n = Bp[(size_t)((s1 + 1) * 8 + wv * 2 + 0) * 64 + l];
            b1n = Bp[(size_t)((s1 + 1) * 8 + wv * 2 + 1) * 64 + l];
        }
#pragma unroll
        for (int mi = 0; mi < 4; ++mi) {
            short8v afr = *(const short8v*)&As[1][16 * mi + arow][crd ^ ((mi & 1) << 2)];
            acc[mi][0] = __builtin_amdgcn_mfma_f32_16x16x32_bf16(afr, b0c, acc[mi][0], 0, 0, 0);
            acc[mi][1] = __builtin_amdgcn_mfma_f32_16x16x32_bf16(afr, b1c, acc[mi][1], 0, 0, 0);
        }
        b0c = b0n; b1c = b1n;
    }

    // epilogue: D layout col = lane&15, row = (lane>>4)*4 + i ; store bf16
    __hip_bfloat16* Ob = fredh + ((size_t)b * HW_ + p0) * MID_;
    const int rbase = 4 * (l >> 4);
    const int ncol0 = 32 * wv + (l & 15);
#pragma unroll
    for (int mi = 0; mi < 4; ++mi)
#pragma unroll
        for (int nb = 0; nb < 2; ++nb)
#pragma unroll
            for (int i = 0; i < 4; ++i) {
                int prow = 16 * mi + rbase + i;
                Ob[(size_t)prow * MID_ + ncol0 + 16 * nb] = __float2bfloat16(acc[mi][nb][i]);
            }
}

// ---------------------------------------------------------------------------
// Kernel 3: per-vertex bilinear gather (bf16 fred) + bias + relu + dot + sigmoid.
// One wave per vertex; lane handles channels 2*lane, 2*lane+1 (one uint load
// per corner). Chunked XCD swizzle: each XCD gets 4 consecutive batches ->
// 1 MB fred slice, L2-resident.
// ---------------------------------------------------------------------------
__global__ __launch_bounds__(256) void k_sample_head(const float* __restrict__ verts,
                                                     const uint* __restrict__ fredu,
                                                     const float* __restrict__ bcomb,
                                                     const float* __restrict__ w2,
                                                     const float* __restrict__ b2,
                                                     float* __restrict__ out) {
    // bijective chunked swizzle: nblocks = 55120 = 8 * 6890
    const int bid  = (blockIdx.x & 7) * (B_ * N_ / 4 / 8) + (blockIdx.x >> 3);
    const int wave = (bid * 256 + (int)threadIdx.x) >> 6;
    const int lane = threadIdx.x & 63;
    if (wave >= B_ * N_) return;
    const int b = wave / N_;
    const int n = wave - b * N_;

    const float u = verts[((size_t)b * N_ + n) * 2 + 0];
    const float v = verts[((size_t)b * N_ + n) * 2 + 1];
    const float x = (u + 1.f) * 0.5f * (float)(W_ - 1);
    const float y = (v + 1.f) * 0.5f * (float)(H_ - 1);
    const float x0f = floorf(x), y0f = floorf(y);
    const float wx = x - x0f, wy = y - y0f;
    const int x0 = (int)x0f, y0 = (int)y0f;
    const int x1 = x0 + 1,   y1 = y0 + 1;

    const float mx0 = (x0 >= 0 && x0 < W_) ? 1.f : 0.f;
    const float mx1 = (x1 >= 0 && x1 < W_) ? 1.f : 0.f;
    const float my0 = (y0 >= 0 && y0 < H_) ? 1.f : 0.f;
    const float my1 = (y1 >= 0 && y1 < H_) ? 1.f : 0.f;

    const int cx0 = min(max(x0, 0), W_ - 1), cx1 = min(max(x1, 0), W_ - 1);
    const int cy0 = min(max(y0, 0), H_ - 1), cy1 = min(max(y1, 0), H_ - 1);

    const float w00 = (1.f - wy) * (1.f - wx) * my0 * mx0;
    const float w01 = (1.f - wy) * wx         * my0 * mx1;
    const float w10 = wy         * (1.f - wx) * my1 * mx0;
    const float w11 = wy         * wx         * my1 * mx1;

    const uint* Fb = fredu + (size_t)b * HW_ * (MID_ / 2);
    const uint u00 = Fb[(size_t)(cy0 * W_ + cx0) * (MID_ / 2) + lane];
    const uint u01 = Fb[(size_t)(cy0 * W_ + cx1) * (MID_ / 2) + lane];
    const uint u10 = Fb[(size_t)(cy1 * W_ + cx0) * (MID_ / 2) + lane];
    const uint u11 = Fb[(size_t)(cy1 * W_ + cx1) * (MID_ / 2) + lane];

    const float2 bc  = ((const float2*)bcomb)[lane];
    const float2 w2v = ((const float2*)w2)[lane];

    const float lo00 = __uint_as_float(u00 << 16), hi00 = __uint_as_float(u00 & 0xffff0000u);
    const float lo01 = __uint_as_float(u01 << 16), hi01 = __uint_as_float(u01 & 0xffff0000u);
    const float lo10 = __uint_as_float(u10 << 16), hi10 = __uint_as_float(u10 & 0xffff0000u);
    const float lo11 = __uint_as_float(u11 << 16), hi11 = __uint_as_float(u11 & 0xffff0000u);

    float hx = lo00 * w00 + lo01 * w01 + lo10 * w10 + lo11 * w11 + bc.x;
    float hy = hi00 * w00 + hi01 * w01 + hi10 * w10 + hi11 * w11 + bc.y;
    hx = fmaxf(hx, 0.f);
    hy = fmaxf(hy, 0.f);

    float s = hx * w2v.x + hy * w2v.y;
#pragma unroll
    for (int off = 32; off >= 1; off >>= 1)
        s += __shfl_xor(s, off);

    if (lane == 0) {
        const float logit = s + b2[0];
        out[wave] = 1.f / (1.f + expf(-logit));
    }
}

// ---------------------------------------------------------------------------
extern "C" void kernel_launch(void* const* d_in, const int* in_sizes, int n_in,
                              void* d_out, int out_size, void* d_ws, size_t ws_size,
                              hipStream_t stream) {
    const float* feat  = (const float*)d_in[0];
    const float* verts = (const float*)d_in[1];
    const float* rw    = (const float*)d_in[2];
    const float* rb    = (const float*)d_in[3];
    const float* w1    = (const float*)d_in[4];
    const float* b1    = (const float*)d_in[5];
    const float* w2    = (const float*)d_in[6];
    const float* b2    = (const float*)d_in[7];
    float* out = (float*)d_out;

    __hip_bfloat16* fredh = (__hip_bfloat16*)d_ws;                 // 32*1024*128 bf16
    __hip_bfloat16* bpack = fredh + (size_t)B_ * HW_ * MID_;       // 1280*128 bf16
    float*          bcomb = (float*)(bpack + (size_t)C_ * MID_);   // 128 f32

    k_wcomb<<<(C_ * MID_) / 256 + 1, 256, 0, stream>>>(rw, w1, b1, rb, bpack, bcomb);

    dim3 g2(HW_ / 64, B_);
    k_pregemm<<<g2, 256, 0, stream>>>(feat, bpack, fredh);

    const int nblk = B_ * N_ / 4;   // 55120, divisible by 8
    k_sample_head<<<nblk, 256, 0, stream>>>(verts, (const uint*)fredh, bcomb, w2, b2, out);
}